// Round 16
// baseline (780.934 us; speedup 1.0000x reference)
//
#include <hip/hip_runtime.h>
#include <hip/hip_bf16.h>
#include <math.h>

#define DD 768
#define HH 384
#define BB 16
#define TT 1024
#define NIH 1152
#define GSP 12  // workgroups per batch in the GRU scan

typedef __attribute__((ext_vector_type(8))) short short8;
typedef __attribute__((ext_vector_type(8))) __bf16 bf16x8;
typedef __attribute__((ext_vector_type(4))) float f32x4;

static __device__ __forceinline__ unsigned short f2bf(float f) {
  unsigned u = __float_as_uint(f);
  u += 0x7fffu + ((u >> 16) & 1u);          // RNE
  return (unsigned short)(u >> 16);
}
static __device__ __forceinline__ float bf2f(unsigned short h) {
  return __uint_as_float(((unsigned)h) << 16);
}
// async global->LDS, 16B per lane; LDS dest = wave-uniform base + lane*16
static __device__ __forceinline__ void gload_lds16(const void* g, void* l) {
  __builtin_amdgcn_global_load_lds(
      (const __attribute__((address_space(1))) unsigned int*)g,
      (__attribute__((address_space(3))) unsigned int*)l, 16, 0, 0);
}

// ---------------- k1a: weight conversion ----------------
__global__ void prep_convert(const float* __restrict__ wgw, const float* __restrict__ wih,
                             const float* __restrict__ whh,
                             unsigned short* __restrict__ wgw_bf, unsigned short* __restrict__ wih_bf,
                             unsigned short* __restrict__ whh_bf)
{
  const int n1 = DD*DD, n2 = NIH*DD, n3 = NIH*HH;
  int stride = gridDim.x * 256;
  for (int idx = blockIdx.x*256 + threadIdx.x; idx < n1+n2+n3; idx += stride) {
    if (idx < n1)            wgw_bf[idx]       = f2bf(wgw[idx]);
    else if (idx < n1+n2)    wih_bf[idx-n1]    = f2bf(wih[idx-n1]);
    else                     whh_bf[idx-n1-n2] = f2bf(whh[idx-n1-n2]);
  }
}

// ---------------- k1b: vL/vR columns (768 blocks) + c0/c1 (block 768) ----------------
__global__ __launch_bounds__(256) void prep_vecs(const float* __restrict__ wgw,
    const float* __restrict__ wgb, const float* __restrict__ aL, const float* __restrict__ aR,
    float* __restrict__ vLR, float* __restrict__ c01)
{
  int tid = threadIdx.x;
  __shared__ float red[8];
  int w = tid >> 6, l = tid & 63;
  if (blockIdx.x < DD) {
    int j = blockIdx.x;
    float al = 0.f, ar = 0.f;
    for (int i = tid; i < DD; i += 256) {
      float wv = wgw[(size_t)i*DD + j];
      al += wv*aL[i]; ar += wv*aR[i];
    }
    for (int off = 32; off; off >>= 1) { al += __shfl_down(al, off); ar += __shfl_down(ar, off); }
    if (l == 0) { red[w*2] = al; red[w*2+1] = ar; }
    __syncthreads();
    if (tid == 0) {
      vLR[j]      = red[0]+red[2]+red[4]+red[6];
      vLR[DD + j] = red[1]+red[3]+red[5]+red[7];
    }
  } else {
    float al = 0.f, ar = 0.f;
    for (int i = tid; i < DD; i += 256) { float bv = wgb[i]; al += bv*aL[i]; ar += bv*aR[i]; }
    for (int off = 32; off; off >>= 1) { al += __shfl_down(al, off); ar += __shfl_down(ar, off); }
    if (l == 0) { red[w*2] = al; red[w*2+1] = ar; }
    __syncthreads();
    if (tid == 0) { c01[0] = red[0]+red[2]+red[4]+red[6]; c01[1] = red[1]+red[3]+red[5]+red[7]; }
  }
}

// ---------------- k2: exact f32 attention scores ----------------
__global__ __launch_bounds__(256) void scores_cvt(const float* __restrict__ emb,
    const float* __restrict__ vLR, const float* __restrict__ c01,
    float* __restrict__ ss, float* __restrict__ sr)
{
  int row = blockIdx.x, tid = threadIdx.x;
  const float* er = emb + (size_t)row*DD;
  float al = 0.f, ar = 0.f;
  for (int d = tid; d < DD; d += 256) {
    float e = er[d];
    al += e*vLR[d]; ar += e*vLR[DD+d];
  }
  for (int off = 32; off; off >>= 1) { al += __shfl_down(al, off); ar += __shfl_down(ar, off); }
  __shared__ float red[8];
  int w = tid >> 6, l = tid & 63;
  if (l == 0) { red[w*2] = al; red[w*2+1] = ar; }
  __syncthreads();
  if (tid == 0) {
    ss[row] = red[0]+red[2]+red[4]+red[6] + c01[0];
    sr[row] = red[1]+red[3]+red[5]+red[7] + c01[1];
  }
}

// ---------------- GEMM: C[m,n] = sum_k A[m,k]*Bw[n,k] + bias[n] ----------------
// m97-style staging: linear [128][32] LDS tiles via global_load_lds (16B/lane).
// B always DMA-staged; A DMA-staged when bf16, reg-staged+converted when f32.
template<bool AF32>
__global__ __launch_bounds__(256) void gemm_bt(const void* __restrict__ Av,
    const unsigned short* __restrict__ Bw, const float* __restrict__ bias,
    unsigned short* __restrict__ C, int N, int MT, int Mreal)
{
  __shared__ __align__(16) unsigned short As[128*32];
  __shared__ __align__(16) unsigned short Bs[128*32];
  int tid = threadIdx.x;
  int tm = blockIdx.x % MT, tn = blockIdx.x / MT;
  int l = tid & 63, lr = l & 15, lk = l >> 4;
  int w = tid >> 6;
  int wm = (w >> 1)*64, wn = (w & 1)*64;
  int ro = l >> 2, co = l & 3;             // lane's row/chunk within a 1024B DMA issue
  f32x4 acc[4][4] = {};

  int c0 = tid, c1 = tid + 256;            // AF32 reg-stage: 512 16B-chunks per tile
  int r0 = c0 >> 2, ch0 = c0 & 3;
  int r1 = c1 >> 2, ch1 = c1 & 3;
  const unsigned short* Bbase = Bw + (size_t)tn*128*DD;

  for (int kt = 0; kt < 24; ++kt) {
    f32x4 a0l, a0h, a1l, a1h;
    if constexpr (AF32) {                   // issue f32 A loads early (overlap prev compute)
      const float* Af = (const float*)Av + (size_t)tm*128*DD;
      a0l = *(const f32x4*)(Af + r0*DD + kt*32 + ch0*8);
      a0h = *(const f32x4*)(Af + r0*DD + kt*32 + ch0*8 + 4);
      a1l = *(const f32x4*)(Af + r1*DD + kt*32 + ch1*8);
      a1h = *(const f32x4*)(Af + r1*DD + kt*32 + ch1*8 + 4);
    }
    __syncthreads();                        // previous iter's LDS reads done
    #pragma unroll
    for (int jj = 0; jj < 2; ++jj) {        // B: 8 x 1024B issues, wave w does 2w,2w+1
      int j = w*2 + jj;
      gload_lds16(Bbase + (j*16 + ro)*DD + kt*32 + co*8, &Bs[j*512]);
    }
    if constexpr (AF32) {
      short8 va0, va1;
      #pragma unroll
      for (int jx = 0; jx < 4; ++jx) {
        va0[jx] = (short)f2bf(a0l[jx]); va0[4+jx] = (short)f2bf(a0h[jx]);
        va1[jx] = (short)f2bf(a1l[jx]); va1[4+jx] = (short)f2bf(a1h[jx]);
      }
      *(short8*)&As[r0*32 + ch0*8] = va0;
      *(short8*)&As[r1*32 + ch1*8] = va1;
    } else {
      const unsigned short* Ab = (const unsigned short*)Av + (size_t)tm*128*DD;
      #pragma unroll
      for (int jj = 0; jj < 2; ++jj) {
        int j = w*2 + jj;
        gload_lds16(Ab + (j*16 + ro)*DD + kt*32 + co*8, &As[j*512]);
      }
    }
    __syncthreads();                        // drains vmcnt+lgkm: LDS tiles ready
    bf16x8 af[4], bfr[4];
    #pragma unroll
    for (int mi = 0; mi < 4; ++mi)
      af[mi] = __builtin_bit_cast(bf16x8, *(const short8*)&As[(wm + mi*16 + lr)*32 + lk*8]);
    #pragma unroll
    for (int ni = 0; ni < 4; ++ni)
      bfr[ni] = __builtin_bit_cast(bf16x8, *(const short8*)&Bs[(wn + ni*16 + lr)*32 + lk*8]);
    #pragma unroll
    for (int mi = 0; mi < 4; ++mi)
      #pragma unroll
      for (int ni = 0; ni < 4; ++ni)
        acc[mi][ni] = __builtin_amdgcn_mfma_f32_16x16x32_bf16(af[mi], bfr[ni], acc[mi][ni], 0, 0, 0);
  }
  // epilogue: D layout col=lane&15, row=(lane>>4)*4+reg
  for (int mi = 0; mi < 4; ++mi) {
    int rbase = tm*128 + wm + mi*16 + lk*4;
    for (int ni = 0; ni < 4; ++ni) {
      int col = tn*128 + wn + ni*16 + lr;
      float bv = bias[col];
      #pragma unroll
      for (int jr = 0; jr < 4; ++jr) {
        int row = rbase + jr;
        if (row < Mreal) C[(size_t)row*N + col] = f2bf(acc[mi][ni][jr] + bv);
      }
    }
  }
}

// ---------------- k4: GAT attention (exact f32 scores) + build G_W (bf16) ----------------
__global__ __launch_bounds__(256) void gat_attn(const float* __restrict__ emb,
    const float* __restrict__ cls, const unsigned short* __restrict__ wgt_bf,
    const float* __restrict__ ss, const float* __restrict__ sr,
    const int* __restrict__ cidx, const int* __restrict__ cmask,
    unsigned short* __restrict__ gw_bf)
{
  int bx = blockIdx.x, tid = threadIdx.x;
  if (bx >= BB*TT) {                       // CLS rows
    int b = bx - BB*TT;
    unsigned short* dst = gw_bf + (size_t)(b*(TT+1))*DD;
    for (int d = tid; d < DD; d += 256) dst[d] = f2bf(cls[d]);
    return;
  }
  int b = bx >> 10, t = bx & 1023;
  __shared__ float sw[8];
  __shared__ int   si[8];
  __shared__ int   sm[8];
  if (tid < 8) {
    int ci = cidx[(size_t)bx*8 + tid];
    int cm = cmask[(size_t)bx*8 + tid];
    float s = ss[bx] + sr[(b<<10) + ci];
    s = s > 0.f ? s : 0.2f*s;              // leaky_relu(0.2)
    sw[tid] = cm ? s : -1e9f;
    si[tid] = ci;
    sm[tid] = cm;
  }
  __syncthreads();
  float a[8];
  float mx = -1e30f;
  #pragma unroll
  for (int k = 0; k < 8; ++k) mx = fmaxf(mx, sw[k]);
  float sum = 0.f;
  #pragma unroll
  for (int k = 0; k < 8; ++k) { a[k] = expf(sw[k]-mx); sum += a[k]; }
  float inv = 1.f/sum;
  #pragma unroll
  for (int k = 0; k < 8; ++k) a[k] = sm[k] ? a[k]*inv : 0.f;
  const float* er = emb + (size_t)bx*DD;
  unsigned short* dst = gw_bf + (size_t)(b*(TT+1) + t + 1)*DD;
  for (int d = tid; d < DD; d += 256) {
    float acc = er[d];
    #pragma unroll
    for (int k = 0; k < 8; ++k)
      if (a[k] != 0.f) acc += a[k]*bf2f(wgt_bf[((size_t)(b<<10) + si[k])*DD + d]);
    dst[d] = f2bf(acc);
  }
}

// ---------------- k6: GRU scan (R5 protocol, GSP=12, 4-deep pipelined poll) ----------------
__global__ __launch_bounds__(384, 2) void gru_scan(const unsigned short* __restrict__ whh_bf,
    const float* __restrict__ bhh, const unsigned short* __restrict__ xp,
    const int* __restrict__ clue, unsigned* __restrict__ hbuf,
    float* __restrict__ hfinal)
{
  __shared__ __align__(16) unsigned short h_bf[HH];
  __shared__ __align__(16) float y_s[96];
  __shared__ float bhh_s[96];
  __shared__ unsigned char m_s[TT+1];
  int tid = threadIdx.x;
  int b = blockIdx.x % BB, g = blockIdx.x / BB;       // g in 0..11
  int w = tid >> 6, l = tid & 63, lr = l & 15, lk = l >> 4;

  // wave w: gate w>>1, sub-rowgroup w&1 -> Whh rows (w>>1)*HH + g*32 + (w&1)*16 + lr
  // areg[c]: chunk kt=(g+c)%12 -> own chunk is always c=0
  bf16x8 areg[12];
  {
    const unsigned short* src = whh_bf + (size_t)((w>>1)*HH + g*32 + (w&1)*16 + lr)*HH;
    #pragma unroll
    for (int c = 0; c < 12; ++c) {
      int kt = g + c; if (kt >= 12) kt -= 12;
      areg[c] = __builtin_bit_cast(bf16x8, *(const short8*)(src + kt*32 + lk*8));
    }
  }
  if (tid < 96) {
    int gate = tid >> 5, e = tid & 31;
    bhh_s[tid] = bhh[gate*HH + g*32 + e];
  }
  h_bf[tid] = 0;                            // 384 threads cover HH exactly
  for (int t = tid; t < TT; t += 384) m_s[t+1] = (clue[b*TT + t] != 0) ? 1 : 0;
  if (tid == 0) m_s[0] = 1;
  __syncthreads();

  float h_prev = 0.f;                       // tid<32 owns h element g*32+tid
  int gi = g*32 + tid;                      // valid for tid<32
  int s = 0;
  int rj = 0;                               // poller's remote element (tid>=32)
  if (tid >= 32) { int e = g*32 + 32 + (tid - 32); if (e >= HH) e -= HH; rj = e; }
  for (int t = 0; t <= TT; ++t) {
    if (!m_s[t]) continue;                  // masked step: h unchanged, skip entirely
    ++s;
    float xr = 0.f, xz = 0.f, xn = 0.f;
    if (tid < 32) {                         // x_proj loads: consumed only in phase 5
      const unsigned short* xrow = xp + (size_t)(b*(TT+1) + t)*NIH;
      xr = bf2f(xrow[gi]); xz = bf2f(xrow[HH + gi]); xn = bf2f(xrow[2*HH + gi]);
    }
    // phase 1: own-k MFMA on state s-1 (chunk 0 = k in [g*32, g*32+32))
    f32x4 aco = {};
    {
      bf16x8 bfr = __builtin_bit_cast(bf16x8, *(const short8*)&h_bf[g*32 + lk*8]);
      aco = __builtin_amdgcn_mfma_f32_16x16x32_bf16(areg[0], bfr, aco, 0, 0, 0);
    }
    // phase 2: pipelined poll — 4 independent loads in flight per poller.
    // Detection granularity ~RTT/4 instead of RTT (dependent-chain retry).
    if (s > 1 && tid >= 32) {
      const unsigned* pa = hbuf + ((size_t)(s-1)*BB + b)*HH + rj;
      unsigned tag = (unsigned)(s-1);
      #define PLD() __hip_atomic_load(pa, __ATOMIC_RELAXED, __HIP_MEMORY_SCOPE_AGENT)
      unsigned v0 = PLD(), v1 = PLD(), v2 = PLD(), v3 = PLD();
      unsigned v;
      for (;;) {
        if ((v0 & 0xFFFFu) == tag) { v = v0; break; }
        v0 = PLD();
        if ((v1 & 0xFFFFu) == tag) { v = v1; break; }
        v1 = PLD();
        if ((v2 & 0xFFFFu) == tag) { v = v2; break; }
        v2 = PLD();
        if ((v3 & 0xFFFFu) == tag) { v = v3; break; }
        v3 = PLD();
      }
      #undef PLD
      h_bf[rj] = (unsigned short)(v >> 16);
    }
    __syncthreads();
    // phase 3: remote-k MFMA, two chains (6 + 5)
    f32x4 acA = {}, acB = {};
    #pragma unroll
    for (int c = 1; c < 7; ++c) {
      int kk = g*32 + c*32; if (kk >= HH) kk -= HH;
      bf16x8 bfr = __builtin_bit_cast(bf16x8, *(const short8*)&h_bf[kk + lk*8]);
      acA = __builtin_amdgcn_mfma_f32_16x16x32_bf16(areg[c], bfr, acA, 0, 0, 0);
    }
    #pragma unroll
    for (int c = 7; c < 12; ++c) {
      int kk = g*32 + c*32; if (kk >= HH) kk -= HH;
      bf16x8 bfr = __builtin_bit_cast(bf16x8, *(const short8*)&h_bf[kk + lk*8]);
      acB = __builtin_amdgcn_mfma_f32_16x16x32_bf16(areg[c], bfr, acB, 0, 0, 0);
    }
    // phase 4: y handoff (y_s[w*16 + r] == y_s[gate*32 + e])
    if (lr == 0) {
      f32x4 ysum = aco + acA + acB;
      *(f32x4*)&y_s[w*16 + lk*4] = ysum;
    }
    __syncthreads();
    // phase 5: gates + coalesced 32-word publish
    unsigned* slot = hbuf + ((size_t)s*BB + b)*HH;
    if (tid < 32) {
      float hr = y_s[tid]      + bhh_s[tid];
      float hz = y_s[32 + tid] + bhh_s[32 + tid];
      float hn = y_s[64 + tid] + bhh_s[64 + tid];
      float rg = 1.f/(1.f + __expf(-(xr + hr)));
      float zg = 1.f/(1.f + __expf(-(xz + hz)));
      float a  = xn + rg*hn;
      a = fminf(fmaxf(a, -15.f), 15.f);
      float e2 = __expf(-2.f*a);
      float ng = (1.f - e2)/(1.f + e2);
      float hnew = (1.f - zg)*ng + zg*h_prev;
      h_prev = hnew;
      unsigned short hb16 = f2bf(hnew);
      h_bf[gi] = hb16;                      // own slice straight to LDS
      __hip_atomic_store(slot + gi, ((unsigned)hb16 << 16) | (unsigned)s,
                         __ATOMIC_RELAXED, __HIP_MEMORY_SCOPE_AGENT);
    }
    __syncthreads();                        // own slice ready for next phase-1
  }
  if (tid < 32) hfinal[b*HH + gi] = h_prev; // exact f32 slice
}

// ---------------- k6b: per-batch head contribution of h_clue ----------------
__global__ __launch_bounds__(384) void hpart_k(const float* __restrict__ hfinal,
    const float* __restrict__ Wc, const float* __restrict__ Wcb,
    const float* __restrict__ We, const float* __restrict__ Web, float* __restrict__ hpart)
{
  int b = blockIdx.x, tid = threadIdx.x;
  int j = tid >> 6, l = tid & 63;
  const float* wr = ((j < 3) ? (Wc + j*NIH) : (We + (j-3)*NIH)) + DD;
  float acc = 0.f;
  #pragma unroll
  for (int i = 0; i < 6; ++i) acc += hfinal[b*HH + l + i*64] * wr[l + i*64];
  for (int off = 32; off; off >>= 1) acc += __shfl_down(acc, off);
  if (l == 0) hpart[b*6 + j] = acc + ((j < 3) ? Wcb[j] : Web[j-3]);
}

// ---------------- k7: cause/effect heads ----------------
__global__ __launch_bounds__(256) void heads(const unsigned short* __restrict__ gw_bf,
    const float* __restrict__ Wc, const float* __restrict__ We,
    const float* __restrict__ hpart, float* __restrict__ out)
{
  __shared__ float Wl[6][DD];
  int tid = threadIdx.x;
  for (int idx = tid; idx < 6*DD; idx += 256) {
    int j = idx / DD, d = idx % DD;
    Wl[j][d] = (j < 3) ? Wc[j*NIH + d] : We[(j-3)*NIH + d];
  }
  __syncthreads();
  int w = tid >> 6, l = tid & 63;
  int row = blockIdx.x*4 + w;
  int b = row >> 10, t = row & 1023;
  const unsigned short* gr = gw_bf + (size_t)(b*(TT+1) + t + 1)*DD;
  float acc[6] = {0,0,0,0,0,0};
  for (int i = 0; i < 12; ++i) {
    int d = l + i*64;
    float v = bf2f(gr[d]);
    #pragma unroll
    for (int j = 0; j < 6; ++j) acc[j] += v * Wl[j][d];
  }
  #pragma unroll
  for (int j = 0; j < 6; ++j)
    for (int off = 32; off; off >>= 1) acc[j] += __shfl_down(acc[j], off);
  if (l == 0) {
    const float* hp = hpart + b*6;
    float* oc = out + (size_t)b*TT*3 + t*3;
    float* oe = out + (size_t)BB*TT*3 + (size_t)b*TT*3 + t*3;
    oc[0] = acc[0]+hp[0]; oc[1] = acc[1]+hp[1]; oc[2] = acc[2]+hp[2];
    oe[0] = acc[3]+hp[3]; oe[1] = acc[4]+hp[4]; oe[2] = acc[5]+hp[5];
  }
}

extern "C" void kernel_launch(void* const* d_in, const int* in_sizes, int n_in,
                              void* d_out, int out_size, void* d_ws, size_t ws_size,
                              hipStream_t stream)
{
  const float* emb  = (const float*)d_in[0];
  const float* cls  = (const float*)d_in[1];
  const float* wgw  = (const float*)d_in[2];
  const float* wgb  = (const float*)d_in[3];
  const float* aL   = (const float*)d_in[4];
  const float* aR   = (const float*)d_in[5];
  const float* wih  = (const float*)d_in[6];
  const float* bih  = (const float*)d_in[7];
  const float* whh  = (const float*)d_in[8];
  const float* bhh  = (const float*)d_in[9];
  const float* wcw  = (const float*)d_in[10];
  const float* wcb  = (const float*)d_in[11];
  const float* wew  = (const float*)d_in[12];
  const float* web  = (const float*)d_in[13];
  const int* cidx   = (const int*)d_in[14];
  const int* cmask  = (const int*)d_in[15];
  const int* clue   = (const int*)d_in[16];
  (void)in_sizes; (void)n_in; (void)out_size; (void)ws_size;

  char* ws = (char*)d_ws;
  size_t off = 0;
  auto alloc = [&](size_t bytes) { char* p = ws + off; off += (bytes + 255) & ~(size_t)255; return p; };
  // regionA: xp_bf (38MB); wgt_bf (25.2MB) aliases its head — disjoint lifetimes
  unsigned short* xp_bf  = (unsigned short*)alloc((size_t)16512*1152*2);
  unsigned short* wgt_bf = xp_bf;
  unsigned short* gw_bf  = (unsigned short*)alloc((size_t)16512*768*2);   // 129*128 rows padded
  unsigned short* wgw_bf = (unsigned short*)alloc((size_t)768*768*2);
  unsigned short* wih_bf = (unsigned short*)alloc((size_t)1152*768*2);
  unsigned short* whh_bf = (unsigned short*)alloc((size_t)1152*384*2);
  float* vLR   = (float*)alloc(1536*4);
  float* c01   = (float*)alloc(256);
  float* ss    = (float*)alloc(16384*4);
  float* sr    = (float*)alloc(16384*4);
  unsigned* hbuf = (unsigned*)alloc((size_t)(TT+2)*BB*HH*4);  // per-step tagged slots, 25.2MB
  float* hfin  = (float*)alloc((size_t)16*384*4);
  float* hpart = (float*)alloc(512);

  prep_convert<<<2048, 256, 0, stream>>>(wgw, wih, whh, wgw_bf, wih_bf, whh_bf);
  prep_vecs<<<DD+1, 256, 0, stream>>>(wgw, wgb, aL, aR, vLR, c01);
  scores_cvt<<<16384, 256, 0, stream>>>(emb, vLR, c01, ss, sr);
  gemm_bt<true><<<128*6, 256, 0, stream>>>(emb, wgw_bf, wgb, wgt_bf, 768, 128, 16384);
  gat_attn<<<16384+16, 256, 0, stream>>>(emb, cls, wgt_bf, ss, sr, cidx, cmask, gw_bf);
  gemm_bt<false><<<129*9, 256, 0, stream>>>(gw_bf, wih_bf, bih, xp_bf, 1152, 129, 16400);
  gru_scan<<<BB*GSP, 384, 0, stream>>>(whh_bf, bhh, xp_bf, clue, hbuf, hfin);
  hpart_k<<<16, 384, 0, stream>>>(hfin, wcw, wcb, wew, web, hpart);
  heads<<<4096, 256, 0, stream>>>(gw_bf, wcw, wew, hpart, (float*)d_out);
}

// Round 17
// 776.311 us; speedup vs baseline: 1.0060x; 1.0060x over previous
//
#include <hip/hip_runtime.h>
#include <hip/hip_bf16.h>
#include <math.h>

#define DD 768
#define HH 384
#define BB 16
#define TT 1024
#define NIH 1152
#define GSP 12  // workgroups per batch in the GRU scan

typedef __attribute__((ext_vector_type(8))) short short8;
typedef __attribute__((ext_vector_type(8))) __bf16 bf16x8;
typedef __attribute__((ext_vector_type(4))) float f32x4;

static __device__ __forceinline__ unsigned short f2bf(float f) {
  unsigned u = __float_as_uint(f);
  u += 0x7fffu + ((u >> 16) & 1u);          // RNE
  return (unsigned short)(u >> 16);
}
static __device__ __forceinline__ float bf2f(unsigned short h) {
  return __uint_as_float(((unsigned)h) << 16);
}
// async global->LDS, 16B per lane; LDS dest = wave-uniform base + lane*16
static __device__ __forceinline__ void gload_lds16(const void* g, void* l) {
  __builtin_amdgcn_global_load_lds(
      (const __attribute__((address_space(1))) unsigned int*)g,
      (__attribute__((address_space(3))) unsigned int*)l, 16, 0, 0);
}

// ---------------- k1a: weight conversion ----------------
__global__ void prep_convert(const float* __restrict__ wgw, const float* __restrict__ wih,
                             const float* __restrict__ whh,
                             unsigned short* __restrict__ wgw_bf, unsigned short* __restrict__ wih_bf,
                             unsigned short* __restrict__ whh_bf)
{
  const int n1 = DD*DD, n2 = NIH*DD, n3 = NIH*HH;
  int stride = gridDim.x * 256;
  for (int idx = blockIdx.x*256 + threadIdx.x; idx < n1+n2+n3; idx += stride) {
    if (idx < n1)            wgw_bf[idx]       = f2bf(wgw[idx]);
    else if (idx < n1+n2)    wih_bf[idx-n1]    = f2bf(wih[idx-n1]);
    else                     whh_bf[idx-n1-n2] = f2bf(whh[idx-n1-n2]);
  }
}

// ---------------- k1b: vL/vR columns (768 blocks) + c0/c1 (block 768) ----------------
__global__ __launch_bounds__(256) void prep_vecs(const float* __restrict__ wgw,
    const float* __restrict__ wgb, const float* __restrict__ aL, const float* __restrict__ aR,
    float* __restrict__ vLR, float* __restrict__ c01)
{
  int tid = threadIdx.x;
  __shared__ float red[8];
  int w = tid >> 6, l = tid & 63;
  if (blockIdx.x < DD) {
    int j = blockIdx.x;
    float al = 0.f, ar = 0.f;
    for (int i = tid; i < DD; i += 256) {
      float wv = wgw[(size_t)i*DD + j];
      al += wv*aL[i]; ar += wv*aR[i];
    }
    for (int off = 32; off; off >>= 1) { al += __shfl_down(al, off); ar += __shfl_down(ar, off); }
    if (l == 0) { red[w*2] = al; red[w*2+1] = ar; }
    __syncthreads();
    if (tid == 0) {
      vLR[j]      = red[0]+red[2]+red[4]+red[6];
      vLR[DD + j] = red[1]+red[3]+red[5]+red[7];
    }
  } else {
    float al = 0.f, ar = 0.f;
    for (int i = tid; i < DD; i += 256) { float bv = wgb[i]; al += bv*aL[i]; ar += bv*aR[i]; }
    for (int off = 32; off; off >>= 1) { al += __shfl_down(al, off); ar += __shfl_down(ar, off); }
    if (l == 0) { red[w*2] = al; red[w*2+1] = ar; }
    __syncthreads();
    if (tid == 0) { c01[0] = red[0]+red[2]+red[4]+red[6]; c01[1] = red[1]+red[3]+red[5]+red[7]; }
  }
}

// ---------------- k2: exact f32 attention scores ----------------
__global__ __launch_bounds__(256) void scores_cvt(const float* __restrict__ emb,
    const float* __restrict__ vLR, const float* __restrict__ c01,
    float* __restrict__ ss, float* __restrict__ sr)
{
  int row = blockIdx.x, tid = threadIdx.x;
  const float* er = emb + (size_t)row*DD;
  float al = 0.f, ar = 0.f;
  for (int d = tid; d < DD; d += 256) {
    float e = er[d];
    al += e*vLR[d]; ar += e*vLR[DD+d];
  }
  for (int off = 32; off; off >>= 1) { al += __shfl_down(al, off); ar += __shfl_down(ar, off); }
  __shared__ float red[8];
  int w = tid >> 6, l = tid & 63;
  if (l == 0) { red[w*2] = al; red[w*2+1] = ar; }
  __syncthreads();
  if (tid == 0) {
    ss[row] = red[0]+red[2]+red[4]+red[6] + c01[0];
    sr[row] = red[1]+red[3]+red[5]+red[7] + c01[1];
  }
}

// ---------------- GEMM: C[m,n] = sum_k A[m,k]*Bw[n,k] + bias[n] ----------------
// m97-style staging: linear [128][32] LDS tiles via global_load_lds (16B/lane).
// B always DMA-staged; A DMA-staged when bf16, reg-staged+converted when f32.
template<bool AF32>
__global__ __launch_bounds__(256) void gemm_bt(const void* __restrict__ Av,
    const unsigned short* __restrict__ Bw, const float* __restrict__ bias,
    unsigned short* __restrict__ C, int N, int MT, int Mreal)
{
  __shared__ __align__(16) unsigned short As[128*32];
  __shared__ __align__(16) unsigned short Bs[128*32];
  int tid = threadIdx.x;
  int tm = blockIdx.x % MT, tn = blockIdx.x / MT;
  int l = tid & 63, lr = l & 15, lk = l >> 4;
  int w = tid >> 6;
  int wm = (w >> 1)*64, wn = (w & 1)*64;
  int ro = l >> 2, co = l & 3;             // lane's row/chunk within a 1024B DMA issue
  f32x4 acc[4][4] = {};

  int c0 = tid, c1 = tid + 256;            // AF32 reg-stage: 512 16B-chunks per tile
  int r0 = c0 >> 2, ch0 = c0 & 3;
  int r1 = c1 >> 2, ch1 = c1 & 3;
  const unsigned short* Bbase = Bw + (size_t)tn*128*DD;

  for (int kt = 0; kt < 24; ++kt) {
    f32x4 a0l, a0h, a1l, a1h;
    if constexpr (AF32) {                   // issue f32 A loads early (overlap prev compute)
      const float* Af = (const float*)Av + (size_t)tm*128*DD;
      a0l = *(const f32x4*)(Af + r0*DD + kt*32 + ch0*8);
      a0h = *(const f32x4*)(Af + r0*DD + kt*32 + ch0*8 + 4);
      a1l = *(const f32x4*)(Af + r1*DD + kt*32 + ch1*8);
      a1h = *(const f32x4*)(Af + r1*DD + kt*32 + ch1*8 + 4);
    }
    __syncthreads();                        // previous iter's LDS reads done
    #pragma unroll
    for (int jj = 0; jj < 2; ++jj) {        // B: 8 x 1024B issues, wave w does 2w,2w+1
      int j = w*2 + jj;
      gload_lds16(Bbase + (j*16 + ro)*DD + kt*32 + co*8, &Bs[j*512]);
    }
    if constexpr (AF32) {
      short8 va0, va1;
      #pragma unroll
      for (int jx = 0; jx < 4; ++jx) {
        va0[jx] = (short)f2bf(a0l[jx]); va0[4+jx] = (short)f2bf(a0h[jx]);
        va1[jx] = (short)f2bf(a1l[jx]); va1[4+jx] = (short)f2bf(a1h[jx]);
      }
      *(short8*)&As[r0*32 + ch0*8] = va0;
      *(short8*)&As[r1*32 + ch1*8] = va1;
    } else {
      const unsigned short* Ab = (const unsigned short*)Av + (size_t)tm*128*DD;
      #pragma unroll
      for (int jj = 0; jj < 2; ++jj) {
        int j = w*2 + jj;
        gload_lds16(Ab + (j*16 + ro)*DD + kt*32 + co*8, &As[j*512]);
      }
    }
    __syncthreads();                        // drains vmcnt+lgkm: LDS tiles ready
    bf16x8 af[4], bfr[4];
    #pragma unroll
    for (int mi = 0; mi < 4; ++mi)
      af[mi] = __builtin_bit_cast(bf16x8, *(const short8*)&As[(wm + mi*16 + lr)*32 + lk*8]);
    #pragma unroll
    for (int ni = 0; ni < 4; ++ni)
      bfr[ni] = __builtin_bit_cast(bf16x8, *(const short8*)&Bs[(wn + ni*16 + lr)*32 + lk*8]);
    #pragma unroll
    for (int mi = 0; mi < 4; ++mi)
      #pragma unroll
      for (int ni = 0; ni < 4; ++ni)
        acc[mi][ni] = __builtin_amdgcn_mfma_f32_16x16x32_bf16(af[mi], bfr[ni], acc[mi][ni], 0, 0, 0);
  }
  // epilogue: D layout col=lane&15, row=(lane>>4)*4+reg
  for (int mi = 0; mi < 4; ++mi) {
    int rbase = tm*128 + wm + mi*16 + lk*4;
    for (int ni = 0; ni < 4; ++ni) {
      int col = tn*128 + wn + ni*16 + lr;
      float bv = bias[col];
      #pragma unroll
      for (int jr = 0; jr < 4; ++jr) {
        int row = rbase + jr;
        if (row < Mreal) C[(size_t)row*N + col] = f2bf(acc[mi][ni][jr] + bv);
      }
    }
  }
}

// ---------------- k4: GAT attention (exact f32 scores) + build G_W (bf16) ----------------
__global__ __launch_bounds__(256) void gat_attn(const float* __restrict__ emb,
    const float* __restrict__ cls, const unsigned short* __restrict__ wgt_bf,
    const float* __restrict__ ss, const float* __restrict__ sr,
    const int* __restrict__ cidx, const int* __restrict__ cmask,
    unsigned short* __restrict__ gw_bf)
{
  int bx = blockIdx.x, tid = threadIdx.x;
  if (bx >= BB*TT) {                       // CLS rows
    int b = bx - BB*TT;
    unsigned short* dst = gw_bf + (size_t)(b*(TT+1))*DD;
    for (int d = tid; d < DD; d += 256) dst[d] = f2bf(cls[d]);
    return;
  }
  int b = bx >> 10, t = bx & 1023;
  __shared__ float sw[8];
  __shared__ int   si[8];
  __shared__ int   sm[8];
  if (tid < 8) {
    int ci = cidx[(size_t)bx*8 + tid];
    int cm = cmask[(size_t)bx*8 + tid];
    float s = ss[bx] + sr[(b<<10) + ci];
    s = s > 0.f ? s : 0.2f*s;              // leaky_relu(0.2)
    sw[tid] = cm ? s : -1e9f;
    si[tid] = ci;
    sm[tid] = cm;
  }
  __syncthreads();
  float a[8];
  float mx = -1e30f;
  #pragma unroll
  for (int k = 0; k < 8; ++k) mx = fmaxf(mx, sw[k]);
  float sum = 0.f;
  #pragma unroll
  for (int k = 0; k < 8; ++k) { a[k] = expf(sw[k]-mx); sum += a[k]; }
  float inv = 1.f/sum;
  #pragma unroll
  for (int k = 0; k < 8; ++k) a[k] = sm[k] ? a[k]*inv : 0.f;
  const float* er = emb + (size_t)bx*DD;
  unsigned short* dst = gw_bf + (size_t)(b*(TT+1) + t + 1)*DD;
  for (int d = tid; d < DD; d += 256) {
    float acc = er[d];
    #pragma unroll
    for (int k = 0; k < 8; ++k)
      if (a[k] != 0.f) acc += a[k]*bf2f(wgt_bf[((size_t)(b<<10) + si[k])*DD + d]);
    dst[d] = f2bf(acc);
  }
}

// ---------------- k6: GRU scan (R5 protocol, GSP=12 — best measured config) ----------------
__global__ __launch_bounds__(384, 2) void gru_scan(const unsigned short* __restrict__ whh_bf,
    const float* __restrict__ bhh, const unsigned short* __restrict__ xp,
    const int* __restrict__ clue, unsigned* __restrict__ hbuf,
    float* __restrict__ hfinal)
{
  __shared__ __align__(16) unsigned short h_bf[HH];
  __shared__ __align__(16) float y_s[96];
  __shared__ float bhh_s[96];
  __shared__ unsigned char m_s[TT+1];
  int tid = threadIdx.x;
  int b = blockIdx.x % BB, g = blockIdx.x / BB;       // g in 0..11
  int w = tid >> 6, l = tid & 63, lr = l & 15, lk = l >> 4;

  // wave w: gate w>>1, sub-rowgroup w&1 -> Whh rows (w>>1)*HH + g*32 + (w&1)*16 + lr
  // areg[c]: chunk kt=(g+c)%12 -> own chunk is always c=0
  bf16x8 areg[12];
  {
    const unsigned short* src = whh_bf + (size_t)((w>>1)*HH + g*32 + (w&1)*16 + lr)*HH;
    #pragma unroll
    for (int c = 0; c < 12; ++c) {
      int kt = g + c; if (kt >= 12) kt -= 12;
      areg[c] = __builtin_bit_cast(bf16x8, *(const short8*)(src + kt*32 + lk*8));
    }
  }
  if (tid < 96) {
    int gate = tid >> 5, e = tid & 31;
    bhh_s[tid] = bhh[gate*HH + g*32 + e];
  }
  h_bf[tid] = 0;                            // 384 threads cover HH exactly
  for (int t = tid; t < TT; t += 384) m_s[t+1] = (clue[b*TT + t] != 0) ? 1 : 0;
  if (tid == 0) m_s[0] = 1;
  __syncthreads();

  float h_prev = 0.f;                       // tid<32 owns h element g*32+tid
  int gi = g*32 + tid;                      // valid for tid<32
  int s = 0;
  int rj = 0;                               // poller's remote element (tid>=32)
  if (tid >= 32) { int e = g*32 + 32 + (tid - 32); if (e >= HH) e -= HH; rj = e; }
  for (int t = 0; t <= TT; ++t) {
    if (!m_s[t]) continue;                  // masked step: h unchanged, skip entirely
    ++s;
    float xr = 0.f, xz = 0.f, xn = 0.f;
    if (tid < 32) {                         // x_proj loads: consumed only in phase 5
      const unsigned short* xrow = xp + (size_t)(b*(TT+1) + t)*NIH;
      xr = bf2f(xrow[gi]); xz = bf2f(xrow[HH + gi]); xn = bf2f(xrow[2*HH + gi]);
    }
    // phase 1: own-k MFMA on state s-1 (chunk 0 = k in [g*32, g*32+32))
    f32x4 aco = {};
    {
      bf16x8 bfr = __builtin_bit_cast(bf16x8, *(const short8*)&h_bf[g*32 + lk*8]);
      aco = __builtin_amdgcn_mfma_f32_16x16x32_bf16(areg[0], bfr, aco, 0, 0, 0);
    }
    // phase 2: 352 pollers fetch remote elements of state s-1
    if (s > 1 && tid >= 32) {
      const unsigned* pa = hbuf + ((size_t)(s-1)*BB + b)*HH + rj;
      unsigned tag = (unsigned)(s-1);
      unsigned v = __hip_atomic_load(pa, __ATOMIC_RELAXED, __HIP_MEMORY_SCOPE_AGENT);
      while ((v & 0xFFFFu) != tag)
        v = __hip_atomic_load(pa, __ATOMIC_RELAXED, __HIP_MEMORY_SCOPE_AGENT);
      h_bf[rj] = (unsigned short)(v >> 16);
    }
    __syncthreads();
    // phase 3: remote-k MFMA, two chains (6 + 5)
    f32x4 acA = {}, acB = {};
    #pragma unroll
    for (int c = 1; c < 7; ++c) {
      int kk = g*32 + c*32; if (kk >= HH) kk -= HH;
      bf16x8 bfr = __builtin_bit_cast(bf16x8, *(const short8*)&h_bf[kk + lk*8]);
      acA = __builtin_amdgcn_mfma_f32_16x16x32_bf16(areg[c], bfr, acA, 0, 0, 0);
    }
    #pragma unroll
    for (int c = 7; c < 12; ++c) {
      int kk = g*32 + c*32; if (kk >= HH) kk -= HH;
      bf16x8 bfr = __builtin_bit_cast(bf16x8, *(const short8*)&h_bf[kk + lk*8]);
      acB = __builtin_amdgcn_mfma_f32_16x16x32_bf16(areg[c], bfr, acB, 0, 0, 0);
    }
    // phase 4: y handoff (y_s[w*16 + r] == y_s[gate*32 + e])
    if (lr == 0) {
      f32x4 ysum = aco + acA + acB;
      *(f32x4*)&y_s[w*16 + lk*4] = ysum;
    }
    __syncthreads();
    // phase 5: gates + coalesced 32-word publish
    unsigned* slot = hbuf + ((size_t)s*BB + b)*HH;
    if (tid < 32) {
      float hr = y_s[tid]      + bhh_s[tid];
      float hz = y_s[32 + tid] + bhh_s[32 + tid];
      float hn = y_s[64 + tid] + bhh_s[64 + tid];
      float rg = 1.f/(1.f + __expf(-(xr + hr)));
      float zg = 1.f/(1.f + __expf(-(xz + hz)));
      float a  = xn + rg*hn;
      a = fminf(fmaxf(a, -15.f), 15.f);
      float e2 = __expf(-2.f*a);
      float ng = (1.f - e2)/(1.f + e2);
      float hnew = (1.f - zg)*ng + zg*h_prev;
      h_prev = hnew;
      unsigned short hb16 = f2bf(hnew);
      h_bf[gi] = hb16;                      // own slice straight to LDS
      __hip_atomic_store(slot + gi, ((unsigned)hb16 << 16) | (unsigned)s,
                         __ATOMIC_RELAXED, __HIP_MEMORY_SCOPE_AGENT);
    }
    __syncthreads();                        // own slice ready for next phase-1
  }
  if (tid < 32) hfinal[b*HH + gi] = h_prev; // exact f32 slice
}

// ---------------- k6b: per-batch head contribution of h_clue ----------------
__global__ __launch_bounds__(384) void hpart_k(const float* __restrict__ hfinal,
    const float* __restrict__ Wc, const float* __restrict__ Wcb,
    const float* __restrict__ We, const float* __restrict__ Web, float* __restrict__ hpart)
{
  int b = blockIdx.x, tid = threadIdx.x;
  int j = tid >> 6, l = tid & 63;
  const float* wr = ((j < 3) ? (Wc + j*NIH) : (We + (j-3)*NIH)) + DD;
  float acc = 0.f;
  #pragma unroll
  for (int i = 0; i < 6; ++i) acc += hfinal[b*HH + l + i*64] * wr[l + i*64];
  for (int off = 32; off; off >>= 1) acc += __shfl_down(acc, off);
  if (l == 0) hpart[b*6 + j] = acc + ((j < 3) ? Wcb[j] : Web[j-3]);
}

// ---------------- k7: cause/effect heads ----------------
__global__ __launch_bounds__(256) void heads(const unsigned short* __restrict__ gw_bf,
    const float* __restrict__ Wc, const float* __restrict__ We,
    const float* __restrict__ hpart, float* __restrict__ out)
{
  __shared__ float Wl[6][DD];
  int tid = threadIdx.x;
  for (int idx = tid; idx < 6*DD; idx += 256) {
    int j = idx / DD, d = idx % DD;
    Wl[j][d] = (j < 3) ? Wc[j*NIH + d] : We[(j-3)*NIH + d];
  }
  __syncthreads();
  int w = tid >> 6, l = tid & 63;
  int row = blockIdx.x*4 + w;
  int b = row >> 10, t = row & 1023;
  const unsigned short* gr = gw_bf + (size_t)(b*(TT+1) + t + 1)*DD;
  float acc[6] = {0,0,0,0,0,0};
  for (int i = 0; i < 12; ++i) {
    int d = l + i*64;
    float v = bf2f(gr[d]);
    #pragma unroll
    for (int j = 0; j < 6; ++j) acc[j] += v * Wl[j][d];
  }
  #pragma unroll
  for (int j = 0; j < 6; ++j)
    for (int off = 32; off; off >>= 1) acc[j] += __shfl_down(acc[j], off);
  if (l == 0) {
    const float* hp = hpart + b*6;
    float* oc = out + (size_t)b*TT*3 + t*3;
    float* oe = out + (size_t)BB*TT*3 + (size_t)b*TT*3 + t*3;
    oc[0] = acc[0]+hp[0]; oc[1] = acc[1]+hp[1]; oc[2] = acc[2]+hp[2];
    oe[0] = acc[3]+hp[3]; oe[1] = acc[4]+hp[4]; oe[2] = acc[5]+hp[5];
  }
}

extern "C" void kernel_launch(void* const* d_in, const int* in_sizes, int n_in,
                              void* d_out, int out_size, void* d_ws, size_t ws_size,
                              hipStream_t stream)
{
  const float* emb  = (const float*)d_in[0];
  const float* cls  = (const float*)d_in[1];
  const float* wgw  = (const float*)d_in[2];
  const float* wgb  = (const float*)d_in[3];
  const float* aL   = (const float*)d_in[4];
  const float* aR   = (const float*)d_in[5];
  const float* wih  = (const float*)d_in[6];
  const float* bih  = (const float*)d_in[7];
  const float* whh  = (const float*)d_in[8];
  const float* bhh  = (const float*)d_in[9];
  const float* wcw  = (const float*)d_in[10];
  const float* wcb  = (const float*)d_in[11];
  const float* wew  = (const float*)d_in[12];
  const float* web  = (const float*)d_in[13];
  const int* cidx   = (const int*)d_in[14];
  const int* cmask  = (const int*)d_in[15];
  const int* clue   = (const int*)d_in[16];
  (void)in_sizes; (void)n_in; (void)out_size; (void)ws_size;

  char* ws = (char*)d_ws;
  size_t off = 0;
  auto alloc = [&](size_t bytes) { char* p = ws + off; off += (bytes + 255) & ~(size_t)255; return p; };
  // regionA: xp_bf (38MB); wgt_bf (25.2MB) aliases its head — disjoint lifetimes
  unsigned short* xp_bf  = (unsigned short*)alloc((size_t)16512*1152*2);
  unsigned short* wgt_bf = xp_bf;
  unsigned short* gw_bf  = (unsigned short*)alloc((size_t)16512*768*2);   // 129*128 rows padded
  unsigned short* wgw_bf = (unsigned short*)alloc((size_t)768*768*2);
  unsigned short* wih_bf = (unsigned short*)alloc((size_t)1152*768*2);
  unsigned short* whh_bf = (unsigned short*)alloc((size_t)1152*384*2);
  float* vLR   = (float*)alloc(1536*4);
  float* c01   = (float*)alloc(256);
  float* ss    = (float*)alloc(16384*4);
  float* sr    = (float*)alloc(16384*4);
  unsigned* hbuf = (unsigned*)alloc((size_t)(TT+2)*BB*HH*4);  // per-step tagged slots, 25.2MB
  float* hfin  = (float*)alloc((size_t)16*384*4);
  float* hpart = (float*)alloc(512);

  prep_convert<<<2048, 256, 0, stream>>>(wgw, wih, whh, wgw_bf, wih_bf, whh_bf);
  prep_vecs<<<DD+1, 256, 0, stream>>>(wgw, wgb, aL, aR, vLR, c01);
  scores_cvt<<<16384, 256, 0, stream>>>(emb, vLR, c01, ss, sr);
  gemm_bt<true><<<128*6, 256, 0, stream>>>(emb, wgw_bf, wgb, wgt_bf, 768, 128, 16384);
  gat_attn<<<16384+16, 256, 0, stream>>>(emb, cls, wgt_bf, ss, sr, cidx, cmask, gw_bf);
  gemm_bt<false><<<129*9, 256, 0, stream>>>(gw_bf, wih_bf, bih, xp_bf, 1152, 129, 16400);
  gru_scan<<<BB*GSP, 384, 0, stream>>>(whh_bf, bhh, xp_bf, clue, hbuf, hfin);
  hpart_k<<<16, 384, 0, stream>>>(hfin, wcw, wcb, wew, web, hpart);
  heads<<<4096, 256, 0, stream>>>(gw_bf, wcw, wew, hpart, (float*)d_out);
}